// Round 1
// baseline (358.684 us; speedup 1.0000x reference)
//
#include <hip/hip_runtime.h>
#include <stdint.h>

typedef unsigned short ushort_t;
typedef __bf16 bf16x8 __attribute__((ext_vector_type(8)));
typedef float  f32x4  __attribute__((ext_vector_type(4)));

#define DEV static __device__ __forceinline__

// fp32 -> bf16 round-to-nearest-even
DEV ushort_t f2bf(float f){
  union { float f; unsigned u; } x; x.f = f;
  unsigned u = x.u;
  return (ushort_t)((u + 0x7fffu + ((u >> 16) & 1u)) >> 16);
}

// Boustrophedon map for S=8192 (g=91): involution, maps permuted<->original.
DEV int hmap(int p){
  int r = p / 91;
  int c = p - r * 91;
  return (r & 1) ? (r * 91 + 90 - c) : p;
}

// async global->LDS 16B per lane (LDS dest must be uniform base + lane*16)
DEV void async16(const void* g, void* l){
  __builtin_amdgcn_global_load_lds(
      (const __attribute__((address_space(1))) unsigned*)g,
      (__attribute__((address_space(3))) unsigned*)l, 16, 0, 0);
}

// ---------------- cast x (fp32 -> bf16), vectorized ----------------
__global__ void cast_kernel(const float* __restrict__ in, ushort_t* __restrict__ out, int n4){
  int i = blockIdx.x * blockDim.x + threadIdx.x;
  if (i < n4){
    float4 v = ((const float4*)in)[i];
    ushort4 o;
    o.x = f2bf(v.x); o.y = f2bf(v.y); o.z = f2bf(v.z); o.w = f2bf(v.w);
    ((ushort4*)out)[i] = o;
  }
}

// ---------- transpose + cast: W [rows][cols] fp32 -> WT [cols][rows] bf16 ----------
__global__ void transpose_cast(const float* __restrict__ W, ushort_t* __restrict__ WT,
                               int rows, int cols){
  __shared__ ushort_t t[64 * 66];   // pad 66: conflict-free column reads
  int tid = threadIdx.x;
  int c0 = blockIdx.x * 64, r0 = blockIdx.y * 64;
  int cl = tid & 63, rb = tid >> 6;
  for (int i = 0; i < 16; ++i){
    int r = rb + i * 4;
    t[r * 66 + cl] = f2bf(W[(size_t)(r0 + r) * cols + c0 + cl]);
  }
  __syncthreads();
  int rr = tid & 63, cb = tid >> 6;
  for (int i = 0; i < 16; ++i){
    int cc = cb + i * 4;
    WT[(size_t)(c0 + cc) * rows + r0 + rr] = t[rr * 66 + cc];
  }
}

// ---------------- m97-style GEMM: C[M][N] = A[M][K] * BT[N][K]^T ----------------
// 128x128 tile, BK=32, 4 waves, each wave a 64x64 quadrant of 4x4 mfma tiles.
template<int OUT_BF16>
__global__ __launch_bounds__(256) void gemm_bt(const ushort_t* __restrict__ A,
                                               const ushort_t* __restrict__ BT,
                                               void* __restrict__ Cout,
                                               int M, int N, int K){
  __shared__ ushort_t As[128 * 32];
  __shared__ ushort_t Bs[128 * 32];
  int tid  = threadIdx.x;
  int lane = tid & 63, w = tid >> 6;
  int qd = lane >> 4, md = lane & 15;
  int m0 = blockIdx.y * 128, n0 = blockIdx.x * 128;
  int wm = (w >> 1) * 64, wn = (w & 1) * 64;

  f32x4 acc[4][4];
  f32x4 z = {0.f, 0.f, 0.f, 0.f};
  for (int a = 0; a < 4; ++a) for (int b = 0; b < 4; ++b) acc[a][b] = z;

  int rowA = m0 + (tid >> 2);
  int rowB = n0 + (tid >> 2);
  int kc8  = (tid & 3) * 8;

  for (int k0 = 0; k0 < K; k0 += 32){
    __syncthreads();   // previous tile's readers done
    async16(&A [(size_t)rowA        * K + k0 + kc8], &As[(size_t)tid * 8]);
    async16(&A [(size_t)(rowA + 64) * K + k0 + kc8], &As[(size_t)(tid + 256) * 8]);
    async16(&BT[(size_t)rowB        * K + k0 + kc8], &Bs[(size_t)tid * 8]);
    async16(&BT[(size_t)(rowB + 64) * K + k0 + kc8], &Bs[(size_t)(tid + 256) * 8]);
    __syncthreads();   // drains vmcnt (compiler emits waitcnt before s_barrier)

    bf16x8 af[4], bg[4];
    for (int mi = 0; mi < 4; ++mi)
      af[mi] = *(const bf16x8*)&As[(wm + mi * 16 + md) * 32 + qd * 8];
    for (int ni = 0; ni < 4; ++ni)
      bg[ni] = *(const bf16x8*)&Bs[(wn + ni * 16 + md) * 32 + qd * 8];
    for (int mi = 0; mi < 4; ++mi)
      for (int ni = 0; ni < 4; ++ni)
        acc[mi][ni] = __builtin_amdgcn_mfma_f32_16x16x32_bf16(af[mi], bg[ni], acc[mi][ni], 0, 0, 0);
  }

  // epilogue: C/D layout col=lane&15, row=quad*4+reg (m89/m91-verified)
  for (int mi = 0; mi < 4; ++mi){
    for (int i = 0; i < 4; ++i){
      int r = m0 + wm + mi * 16 + qd * 4 + i;
      size_t base = (size_t)r * N + n0 + wn;
      for (int ni = 0; ni < 4; ++ni){
        float v = acc[mi][ni][i];
        if (OUT_BF16) ((ushort_t*)Cout)[base + ni * 16 + md] = f2bf(v);
        else          ((float*)   Cout)[base + ni * 16 + md] = v;
      }
    }
  }
}

// ---------------- fused segment attention ----------------
// grid (nseg=64, H=16, B=2), block 256 (4 waves). qkv: [16384][3072] bf16 natural
// seq order (cols: 0..1023 Q, 1024..2047 K, 2048..3071 V, each h*64+d).
// Permutation + dilation folded into the gathers; output written back to
// natural order aout[16384][1024] (col = h*64+d).
__global__ __launch_bounds__(256) void attn_kernel(const ushort_t* __restrict__ qkv,
                                                   ushort_t* __restrict__ aout){
  __shared__ ushort_t Qs[128 * 72];   // reused as P after scores (wave-private rows)
  __shared__ ushort_t Ks[64 * 72];
  __shared__ ushort_t Vt[64 * 72];    // V transposed: Vt[d][kidx]
  int tid  = threadIdx.x;
  int lane = tid & 63, w = tid >> 6;
  int qd = lane >> 4, md = lane & 15;
  int seg = blockIdx.x, h = blockIdx.y, b = blockIdx.z;
  int rowbase = b * 8192;
  int p0 = seg * 128;

  // Q: 128 rows x 64 bf16 (8 chunks of 16B per row)
  for (int it = 0; it < 4; ++it){
    int q = it * 256 + tid;
    int r = q >> 3, ch = q & 7;
    int s = hmap(p0 + r);
    uint4 d = *(const uint4*)&qkv[(size_t)(rowbase + s) * 3072 + h * 64 + ch * 8];
    *(uint4*)&Qs[r * 72 + ch * 8] = d;
  }
  // K (dilated: permuted positions p0 + 2*j)
  for (int it = 0; it < 2; ++it){
    int q = it * 256 + tid;
    int r = q >> 3, ch = q & 7;
    int s = hmap(p0 + 2 * r);
    uint4 d = *(const uint4*)&qkv[(size_t)(rowbase + s) * 3072 + 1024 + h * 64 + ch * 8];
    *(uint4*)&Ks[r * 72 + ch * 8] = d;
  }
  // V (dilated), stored transposed for the PV B-operand
  for (int it = 0; it < 2; ++it){
    int q = it * 256 + tid;
    int r = q >> 3, ch = q & 7;
    int s = hmap(p0 + 2 * r);
    union { uint4 v; ushort_t u[8]; } d;
    d.v = *(const uint4*)&qkv[(size_t)(rowbase + s) * 3072 + 2048 + h * 64 + ch * 8];
    for (int e = 0; e < 8; ++e) Vt[(ch * 8 + e) * 72 + r] = d.u[e];
  }
  __syncthreads();

  // scores: wave w owns q-rows [32w, 32w+32): 2 row-tiles x 4 col-tiles
  f32x4 z = {0.f, 0.f, 0.f, 0.f};
  f32x4 sc[2][4];
  for (int mi = 0; mi < 2; ++mi) for (int ni = 0; ni < 4; ++ni) sc[mi][ni] = z;
  for (int kc = 0; kc < 2; ++kc){
    bf16x8 aq[2], bk[4];
    for (int mi = 0; mi < 2; ++mi)
      aq[mi] = *(const bf16x8*)&Qs[(w * 32 + mi * 16 + md) * 72 + kc * 32 + qd * 8];
    for (int ni = 0; ni < 4; ++ni)
      bk[ni] = *(const bf16x8*)&Ks[(ni * 16 + md) * 72 + kc * 32 + qd * 8];
    for (int mi = 0; mi < 2; ++mi)
      for (int ni = 0; ni < 4; ++ni)
        sc[mi][ni] = __builtin_amdgcn_mfma_f32_16x16x32_bf16(aq[mi], bk[ni], sc[mi][ni], 0, 0, 0);
  }

  // softmax over 64 keys; scale 1/sqrt(64)=0.125. Row r lives in 16 lanes
  // (same quad) x 4 col-tiles -> in-register + shfl_xor(1,2,4,8) reduction.
  const float scale = 0.125f;
  ushort_t* Ps = Qs;  // alias: wave only touches its own 32 rows
  for (int mi = 0; mi < 2; ++mi){
    for (int i = 0; i < 4; ++i){
      float mx = sc[mi][0][i];
      for (int ni = 1; ni < 4; ++ni) mx = fmaxf(mx, sc[mi][ni][i]);
      for (int d = 1; d < 16; d <<= 1) mx = fmaxf(mx, __shfl_xor(mx, d));
      float e[4], sum = 0.f;
      for (int ni = 0; ni < 4; ++ni){ e[ni] = __expf((sc[mi][ni][i] - mx) * scale); sum += e[ni]; }
      for (int d = 1; d < 16; d <<= 1) sum += __shfl_xor(sum, d);
      float inv = 1.0f / sum;
      int r = w * 32 + mi * 16 + qd * 4 + i;
      for (int ni = 0; ni < 4; ++ni)
        Ps[r * 72 + ni * 16 + md] = f2bf(e[ni] * inv);
    }
  }

  // O = P @ V : A = P (rows w*32..+31), B = Vt[d][k]
  f32x4 oc[2][4];
  for (int mi = 0; mi < 2; ++mi) for (int ni = 0; ni < 4; ++ni) oc[mi][ni] = z;
  for (int kc = 0; kc < 2; ++kc){
    bf16x8 ap[2], bv[4];
    for (int mi = 0; mi < 2; ++mi)
      ap[mi] = *(const bf16x8*)&Ps[(w * 32 + mi * 16 + md) * 72 + kc * 32 + qd * 8];
    for (int ni = 0; ni < 4; ++ni)
      bv[ni] = *(const bf16x8*)&Vt[(ni * 16 + md) * 72 + kc * 32 + qd * 8];
    for (int mi = 0; mi < 2; ++mi)
      for (int ni = 0; ni < 4; ++ni)
        oc[mi][ni] = __builtin_amdgcn_mfma_f32_16x16x32_bf16(ap[mi], bv[ni], oc[mi][ni], 0, 0, 0);
  }

  // scatter back to natural seq order (inverse perm == hmap, involution)
  for (int mi = 0; mi < 2; ++mi){
    for (int i = 0; i < 4; ++i){
      int rl = w * 32 + mi * 16 + qd * 4 + i;
      int s  = hmap(p0 + rl);
      size_t base = (size_t)(rowbase + s) * 1024 + h * 64;
      for (int ni = 0; ni < 4; ++ni)
        aout[base + ni * 16 + md] = f2bf(oc[mi][ni][i]);
    }
  }
}

extern "C" void kernel_launch(void* const* d_in, const int* in_sizes, int n_in,
                              void* d_out, int out_size, void* d_ws, size_t ws_size,
                              hipStream_t stream){
  const float* x    = (const float*)d_in[0];   // [2,8192,1024]
  const float* Wqkv = (const float*)d_in[1];   // [1024,3072]
  const float* Wout = (const float*)d_in[2];   // [1024,1024]
  float* out = (float*)d_out;                  // [2,8192,1024]

  // workspace layout (bytes): xb 32M | WqT 6M | WoT 2M | qkv 96M | aout 32M = 168 MB
  char* ws = (char*)d_ws;
  ushort_t* xb    = (ushort_t*)(ws);
  ushort_t* WqT   = (ushort_t*)(ws + 33554432);
  ushort_t* WoT   = (ushort_t*)(ws + 33554432 + 6291456);
  ushort_t* qkvb  = (ushort_t*)(ws + 33554432 + 6291456 + 2097152);
  ushort_t* aoutb = (ushort_t*)(ws + 33554432 + 6291456 + 2097152 + 100663296);

  cast_kernel<<<16384, 256, 0, stream>>>(x, xb, (16384 * 1024) / 4);
  transpose_cast<<<dim3(48, 16), 256, 0, stream>>>(Wqkv, WqT, 1024, 3072);
  transpose_cast<<<dim3(16, 16), 256, 0, stream>>>(Wout, WoT, 1024, 1024);
  gemm_bt<1><<<dim3(24, 128), 256, 0, stream>>>(xb, WqT, qkvb, 16384, 3072, 1024);
  attn_kernel<<<dim3(64, 16, 2), 256, 0, stream>>>(qkvb, aoutb);
  gemm_bt<0><<<dim3(8, 128), 256, 0, stream>>>(aoutb, WoT, out, 16384, 1024, 1024);
}

// Round 2
// 335.215 us; speedup vs baseline: 1.0700x; 1.0700x over previous
//
#include <hip/hip_runtime.h>
#include <stdint.h>

typedef unsigned short ushort_t;
typedef __bf16 bf16x8 __attribute__((ext_vector_type(8)));
typedef float  f32x4  __attribute__((ext_vector_type(4)));
typedef float  f32x16 __attribute__((ext_vector_type(16)));

#define DEV static __device__ __forceinline__

// fp32 -> bf16 round-to-nearest-even
DEV ushort_t f2bf(float f){
  union { float f; unsigned u; } x; x.f = f;
  unsigned u = x.u;
  return (ushort_t)((u + 0x7fffu + ((u >> 16) & 1u)) >> 16);
}

// Boustrophedon map for S=8192 (g=91): involution, maps permuted<->original.
DEV int hmap(int p){
  int r = p / 91;
  int c = p - r * 91;
  return (r & 1) ? (r * 91 + 90 - c) : p;
}

// async global->LDS 16B per lane (LDS dest must be uniform base + lane*16)
DEV void async16(const void* g, void* l){
  __builtin_amdgcn_global_load_lds(
      (const __attribute__((address_space(1))) unsigned*)g,
      (__attribute__((address_space(3))) unsigned*)l, 16, 0, 0);
}

// ---------------- cast x (fp32 -> bf16), vectorized ----------------
__global__ void cast_kernel(const float* __restrict__ in, ushort_t* __restrict__ out, int n4){
  int i = blockIdx.x * blockDim.x + threadIdx.x;
  if (i < n4){
    float4 v = ((const float4*)in)[i];
    ushort4 o;
    o.x = f2bf(v.x); o.y = f2bf(v.y); o.z = f2bf(v.z); o.w = f2bf(v.w);
    ((ushort4*)out)[i] = o;
  }
}

// ---------- transpose + cast: W [rows][cols] fp32 -> WT [cols][rows] bf16 ----------
__global__ void transpose_cast(const float* __restrict__ W, ushort_t* __restrict__ WT,
                               int rows, int cols){
  __shared__ ushort_t t[64 * 66];   // pad 66: conflict-free column reads
  int tid = threadIdx.x;
  int c0 = blockIdx.x * 64, r0 = blockIdx.y * 64;
  int cl = tid & 63, rb = tid >> 6;
  for (int i = 0; i < 16; ++i){
    int r = rb + i * 4;
    t[r * 66 + cl] = f2bf(W[(size_t)(r0 + r) * cols + c0 + cl]);
  }
  __syncthreads();
  int rr = tid & 63, cb = tid >> 6;
  for (int i = 0; i < 16; ++i){
    int cc = cb + i * 4;
    WT[(size_t)(c0 + cc) * rows + r0 + rr] = t[rr * 66 + cc];
  }
}

// ---------------- GEMM: C[M][N] = A[M][K] * BT[N][K]^T ----------------
// 128x128 tile, BK=32, 4 waves, each wave a 64x64 quadrant of 2x2 mfma
// 32x32x16 tiles. LDS rows are 64 B = 4 x 16B chunks; physical chunk slot is
// XOR-swizzled: slot = chunk ^ ((row>>1)&3) -> 8 consecutive lanes of a
// ds_read_b128 hit 8 distinct 4-bank groups (all 32 banks, conflict-free),
// while global_load_lds keeps its required contiguous dest (base + lane*16):
// the staging thread just fetches the permuted *global* chunk.
template<int OUT_BF16>
__global__ __launch_bounds__(256) void gemm_bt(const ushort_t* __restrict__ A,
                                               const ushort_t* __restrict__ BT,
                                               void* __restrict__ Cout,
                                               int M, int N, int K){
  __shared__ ushort_t As[128 * 32];
  __shared__ ushort_t Bs[128 * 32];
  int tid  = threadIdx.x;
  int lane = tid & 63, w = tid >> 6;
  int l31 = lane & 31, lh = lane >> 5;
  int m0 = blockIdx.y * 128, n0 = blockIdx.x * 128;
  int wm = (w >> 1) * 64, wn = (w & 1) * 64;

  f32x16 acc[2][2];
  for (int a = 0; a < 4; ++a) for (int b = 0; b < 16; ++b) acc[a >> 1][a & 1][b] = 0.f;

  int rowA = m0 + (tid >> 2);
  int rowB = n0 + (tid >> 2);
  int xc8  = ((tid & 3) ^ ((tid >> 3) & 3)) * 8;   // swizzled global chunk (elems)

  // fragment LDS offsets (ushort units), k0-independent
  int aoff[2][2], boff[2][2];
  for (int mi = 0; mi < 2; ++mi){
    int r = wm + mi * 32 + l31;
    int sw = (r >> 1) & 3;
    for (int kc = 0; kc < 2; ++kc)
      aoff[mi][kc] = r * 32 + ((kc * 2 + lh) ^ sw) * 8;
  }
  for (int ni = 0; ni < 2; ++ni){
    int r = wn + ni * 32 + l31;
    int sw = (r >> 1) & 3;
    for (int kc = 0; kc < 2; ++kc)
      boff[ni][kc] = r * 32 + ((kc * 2 + lh) ^ sw) * 8;
  }

  for (int k0 = 0; k0 < K; k0 += 32){
    __syncthreads();   // previous tile's readers done
    async16(&A [(size_t)rowA        * K + k0 + xc8], &As[(size_t)tid * 8]);
    async16(&A [(size_t)(rowA + 64) * K + k0 + xc8], &As[(size_t)(tid + 256) * 8]);
    async16(&BT[(size_t)rowB        * K + k0 + xc8], &Bs[(size_t)tid * 8]);
    async16(&BT[(size_t)(rowB + 64) * K + k0 + xc8], &Bs[(size_t)(tid + 256) * 8]);
    __syncthreads();   // drains vmcnt (compiler emits waitcnt before s_barrier)

    bf16x8 af[2][2], bg[2][2];
    #pragma unroll
    for (int mi = 0; mi < 2; ++mi)
      #pragma unroll
      for (int kc = 0; kc < 2; ++kc)
        af[mi][kc] = *(const bf16x8*)&As[aoff[mi][kc]];
    #pragma unroll
    for (int ni = 0; ni < 2; ++ni)
      #pragma unroll
      for (int kc = 0; kc < 2; ++kc)
        bg[ni][kc] = *(const bf16x8*)&Bs[boff[ni][kc]];

    #pragma unroll
    for (int kc = 0; kc < 2; ++kc)
      #pragma unroll
      for (int mi = 0; mi < 2; ++mi)
        #pragma unroll
        for (int ni = 0; ni < 2; ++ni)
          acc[mi][ni] = __builtin_amdgcn_mfma_f32_32x32x16_bf16(af[mi][kc], bg[ni][kc], acc[mi][ni], 0, 0, 0);
  }

  // epilogue: 32x32 C/D layout col=lane&31, row=(reg&3)+8*(reg>>2)+4*(lane>>5)
  // (m74/m101-verified). Half-wave writes 32 consecutive elements per reg.
  #pragma unroll
  for (int mi = 0; mi < 2; ++mi){
    #pragma unroll
    for (int ni = 0; ni < 2; ++ni){
      f32x16 v = acc[mi][ni];
      #pragma unroll
      for (int reg = 0; reg < 16; ++reg){
        int r = m0 + wm + mi * 32 + (reg & 3) + 8 * (reg >> 2) + 4 * lh;
        size_t idx = (size_t)r * N + n0 + wn + ni * 32 + l31;
        if (OUT_BF16) ((ushort_t*)Cout)[idx] = f2bf(v[reg]);
        else          ((float*)   Cout)[idx] = v[reg];
      }
    }
  }
}

// ---------------- fused segment attention ----------------
// grid (nseg=64, H=16, B=2), block 256 (4 waves). qkv: [16384][3072] bf16 natural
// seq order (cols: 0..1023 Q, 1024..2047 K, 2048..3071 V, each h*64+d).
// Permutation + dilation folded into the gathers; output written back to
// natural order aout[16384][1024] (col = h*64+d).
__global__ __launch_bounds__(256) void attn_kernel(const ushort_t* __restrict__ qkv,
                                                   ushort_t* __restrict__ aout){
  __shared__ ushort_t Qs[128 * 72];   // reused as P after scores (wave-private rows)
  __shared__ ushort_t Ks[64 * 72];
  __shared__ ushort_t Vt[64 * 72];    // V transposed: Vt[d][kidx]
  int tid  = threadIdx.x;
  int lane = tid & 63, w = tid >> 6;
  int qd = lane >> 4, md = lane & 15;
  int seg = blockIdx.x, h = blockIdx.y, b = blockIdx.z;
  int rowbase = b * 8192;
  int p0 = seg * 128;

  // Q: 128 rows x 64 bf16 (8 chunks of 16B per row)
  for (int it = 0; it < 4; ++it){
    int q = it * 256 + tid;
    int r = q >> 3, ch = q & 7;
    int s = hmap(p0 + r);
    uint4 d = *(const uint4*)&qkv[(size_t)(rowbase + s) * 3072 + h * 64 + ch * 8];
    *(uint4*)&Qs[r * 72 + ch * 8] = d;
  }
  // K (dilated: permuted positions p0 + 2*j)
  for (int it = 0; it < 2; ++it){
    int q = it * 256 + tid;
    int r = q >> 3, ch = q & 7;
    int s = hmap(p0 + 2 * r);
    uint4 d = *(const uint4*)&qkv[(size_t)(rowbase + s) * 3072 + 1024 + h * 64 + ch * 8];
    *(uint4*)&Ks[r * 72 + ch * 8] = d;
  }
  // V (dilated), stored transposed for the PV B-operand
  for (int it = 0; it < 2; ++it){
    int q = it * 256 + tid;
    int r = q >> 3, ch = q & 7;
    int s = hmap(p0 + 2 * r);
    union { uint4 v; ushort_t u[8]; } d;
    d.v = *(const uint4*)&qkv[(size_t)(rowbase + s) * 3072 + 2048 + h * 64 + ch * 8];
    for (int e = 0; e < 8; ++e) Vt[(ch * 8 + e) * 72 + r] = d.u[e];
  }
  __syncthreads();

  // scores: wave w owns q-rows [32w, 32w+32): 2 row-tiles x 4 col-tiles
  f32x4 z = {0.f, 0.f, 0.f, 0.f};
  f32x4 sc[2][4];
  for (int mi = 0; mi < 2; ++mi) for (int ni = 0; ni < 4; ++ni) sc[mi][ni] = z;
  for (int kc = 0; kc < 2; ++kc){
    bf16x8 aq[2], bk[4];
    for (int mi = 0; mi < 2; ++mi)
      aq[mi] = *(const bf16x8*)&Qs[(w * 32 + mi * 16 + md) * 72 + kc * 32 + qd * 8];
    for (int ni = 0; ni < 4; ++ni)
      bk[ni] = *(const bf16x8*)&Ks[(ni * 16 + md) * 72 + kc * 32 + qd * 8];
    for (int mi = 0; mi < 2; ++mi)
      for (int ni = 0; ni < 4; ++ni)
        sc[mi][ni] = __builtin_amdgcn_mfma_f32_16x16x32_bf16(aq[mi], bk[ni], sc[mi][ni], 0, 0, 0);
  }

  // softmax over 64 keys; scale 1/sqrt(64)=0.125. Row r lives in 16 lanes
  // (same quad) x 4 col-tiles -> in-register + shfl_xor(1,2,4,8) reduction.
  const float scale = 0.125f;
  ushort_t* Ps = Qs;  // alias: wave only touches its own 32 rows
  for (int mi = 0; mi < 2; ++mi){
    for (int i = 0; i < 4; ++i){
      float mx = sc[mi][0][i];
      for (int ni = 1; ni < 4; ++ni) mx = fmaxf(mx, sc[mi][ni][i]);
      for (int d = 1; d < 16; d <<= 1) mx = fmaxf(mx, __shfl_xor(mx, d));
      float e[4], sum = 0.f;
      for (int ni = 0; ni < 4; ++ni){ e[ni] = __expf((sc[mi][ni][i] - mx) * scale); sum += e[ni]; }
      for (int d = 1; d < 16; d <<= 1) sum += __shfl_xor(sum, d);
      float inv = 1.0f / sum;
      int r = w * 32 + mi * 16 + qd * 4 + i;
      for (int ni = 0; ni < 4; ++ni)
        Ps[r * 72 + ni * 16 + md] = f2bf(e[ni] * inv);
    }
  }

  // O = P @ V : A = P (rows w*32..+31), B = Vt[d][k]
  f32x4 oc[2][4];
  for (int mi = 0; mi < 2; ++mi) for (int ni = 0; ni < 4; ++ni) oc[mi][ni] = z;
  for (int kc = 0; kc < 2; ++kc){
    bf16x8 ap[2], bv[4];
    for (int mi = 0; mi < 2; ++mi)
      ap[mi] = *(const bf16x8*)&Ps[(w * 32 + mi * 16 + md) * 72 + kc * 32 + qd * 8];
    for (int ni = 0; ni < 4; ++ni)
      bv[ni] = *(const bf16x8*)&Vt[(ni * 16 + md) * 72 + kc * 32 + qd * 8];
    for (int mi = 0; mi < 2; ++mi)
      for (int ni = 0; ni < 4; ++ni)
        oc[mi][ni] = __builtin_amdgcn_mfma_f32_16x16x32_bf16(ap[mi], bv[ni], oc[mi][ni], 0, 0, 0);
  }

  // scatter back to natural seq order (inverse perm == hmap, involution)
  for (int mi = 0; mi < 2; ++mi){
    for (int i = 0; i < 4; ++i){
      int rl = w * 32 + mi * 16 + qd * 4 + i;
      int s  = hmap(p0 + rl);
      size_t base = (size_t)(rowbase + s) * 1024 + h * 64;
      for (int ni = 0; ni < 4; ++ni)
        aout[base + ni * 16 + md] = f2bf(oc[mi][ni][i]);
    }
  }
}

extern "C" void kernel_launch(void* const* d_in, const int* in_sizes, int n_in,
                              void* d_out, int out_size, void* d_ws, size_t ws_size,
                              hipStream_t stream){
  const float* x    = (const float*)d_in[0];   // [2,8192,1024]
  const float* Wqkv = (const float*)d_in[1];   // [1024,3072]
  const float* Wout = (const float*)d_in[2];   // [1024,1024]
  float* out = (float*)d_out;                  // [2,8192,1024]

  // workspace layout (bytes): xb 32M | WqT 6M | WoT 2M | qkv 96M | aout 32M = 168 MB
  char* ws = (char*)d_ws;
  ushort_t* xb    = (ushort_t*)(ws);
  ushort_t* WqT   = (ushort_t*)(ws + 33554432);
  ushort_t* WoT   = (ushort_t*)(ws + 33554432 + 6291456);
  ushort_t* qkvb  = (ushort_t*)(ws + 33554432 + 6291456 + 2097152);
  ushort_t* aoutb = (ushort_t*)(ws + 33554432 + 6291456 + 2097152 + 100663296);

  cast_kernel<<<16384, 256, 0, stream>>>(x, xb, (16384 * 1024) / 4);
  transpose_cast<<<dim3(48, 16), 256, 0, stream>>>(Wqkv, WqT, 1024, 3072);
  transpose_cast<<<dim3(16, 16), 256, 0, stream>>>(Wout, WoT, 1024, 1024);
  gemm_bt<1><<<dim3(24, 128), 256, 0, stream>>>(xb, WqT, qkvb, 16384, 3072, 1024);
  attn_kernel<<<dim3(64, 16, 2), 256, 0, stream>>>(qkvb, aoutb);
  gemm_bt<0><<<dim3(8, 128), 256, 0, stream>>>(aoutb, WoT, out, 16384, 1024, 1024);
}

// Round 3
// 314.734 us; speedup vs baseline: 1.1396x; 1.0651x over previous
//
#include <hip/hip_runtime.h>
#include <stdint.h>

typedef unsigned short ushort_t;
typedef __bf16 bf16x8 __attribute__((ext_vector_type(8)));
typedef float  f32x4  __attribute__((ext_vector_type(4)));
typedef float  f32x16 __attribute__((ext_vector_type(16)));

#define DEV static __device__ __forceinline__

// fp32 -> bf16 round-to-nearest-even
DEV ushort_t f2bf(float f){
  union { float f; unsigned u; } x; x.f = f;
  unsigned u = x.u;
  return (ushort_t)((u + 0x7fffu + ((u >> 16) & 1u)) >> 16);
}

// Boustrophedon map for S=8192 (g=91): involution, maps permuted<->original.
DEV int hmap(int p){
  int r = p / 91;
  int c = p - r * 91;
  return (r & 1) ? (r * 91 + 90 - c) : p;
}

// async global->LDS 16B per lane (LDS dest must be uniform base + lane*16)
DEV void async16(const void* g, void* l){
  __builtin_amdgcn_global_load_lds(
      (const __attribute__((address_space(1))) unsigned*)g,
      (__attribute__((address_space(3))) unsigned*)l, 16, 0, 0);
}

// A-row gather modes: 0 identity; 1 = Q permuted order (row p of batch b reads
// natural row hmap(p)); 2 = compacted dilated KV order (row seg*64+j of batch b
// reads natural row hmap(seg*128+2j)).
template<int GATHER>
DEV int arow_map(int r){
  if (GATHER == 0) return r;
  if (GATHER == 1){ int b = r >> 13, p = r & 8191; return b * 8192 + hmap(p); }
  int b = r >> 12, rem = r & 4095, seg = rem >> 6, j = rem & 63;
  return b * 8192 + hmap(seg * 128 + 2 * j);
}

// ---------------- cast x (fp32 -> bf16), vectorized ----------------
__global__ void cast_kernel(const float* __restrict__ in, ushort_t* __restrict__ out, int n4){
  int i = blockIdx.x * blockDim.x + threadIdx.x;
  if (i < n4){
    float4 v = ((const float4*)in)[i];
    ushort4 o;
    o.x = f2bf(v.x); o.y = f2bf(v.y); o.z = f2bf(v.z); o.w = f2bf(v.w);
    ((ushort4*)out)[i] = o;
  }
}

// ---------- transpose + cast: W [rows][cols] fp32 -> WT [cols][rows] bf16 ----------
__global__ void transpose_cast(const float* __restrict__ W, ushort_t* __restrict__ WT,
                               int rows, int cols){
  __shared__ ushort_t t[64 * 66];   // pad 66: conflict-free column reads
  int tid = threadIdx.x;
  int c0 = blockIdx.x * 64, r0 = blockIdx.y * 64;
  int cl = tid & 63, rb = tid >> 6;
  for (int i = 0; i < 16; ++i){
    int r = rb + i * 4;
    t[r * 66 + cl] = f2bf(W[(size_t)(r0 + r) * cols + c0 + cl]);
  }
  __syncthreads();
  int rr = tid & 63, cb = tid >> 6;
  for (int i = 0; i < 16; ++i){
    int cc = cb + i * 4;
    WT[(size_t)(c0 + cc) * rows + r0 + rr] = t[rr * 66 + cc];
  }
}

// ---------------- GEMM: C[M][N] = A[gather(M)][K] * BT[N][K]^T ----------------
// 128x128 tile, BK=64 (halves barrier drains vs BK=32), 4 waves, each wave a
// 64x64 quadrant of 2x2 mfma 32x32x16 tiles. LDS rows: 64 elems = 8 x 16B
// chunks, physical slot = chunk ^ (row&7) -> fragment ds_read_b128 spreads 8
// consecutive rows over all 32 banks. global_load_lds keeps contiguous dest
// (base + lane*16); the staging thread fetches the permuted *global* chunk.
template<int OUT_BF16, int GATHER>
__global__ __launch_bounds__(256) void gemm_bt(const ushort_t* __restrict__ A,
                                               const ushort_t* __restrict__ BT,
                                               void* __restrict__ Cout,
                                               int M, int N, int K){
  __shared__ ushort_t As[128 * 64];
  __shared__ ushort_t Bs[128 * 64];
  int tid  = threadIdx.x;
  int lane = tid & 63, w = tid >> 6;
  int l31 = lane & 31, lh = lane >> 5;
  int m0 = blockIdx.y * 128, n0 = blockIdx.x * 128;
  int wm = (w >> 1) * 64, wn = (w & 1) * 64;

  f32x16 acc[2][2];
  for (int a = 0; a < 4; ++a) for (int b = 0; b < 16; ++b) acc[a >> 1][a & 1][b] = 0.f;

  // staging plan: instr i (0..3) covers linear chunk q=256*i+tid ->
  // row = 32*i + (tid>>3), dest slot = tid&7, global chunk = slot ^ (row&7).
  int rbase = tid >> 3, slot = tid & 7;
  size_t asrc[4], bsrc[4];
  #pragma unroll
  for (int i = 0; i < 4; ++i){
    int r = rbase + 32 * i;
    int g = slot ^ (r & 7);
    asrc[i] = (size_t)arow_map<GATHER>(m0 + r) * K + g * 8;
    bsrc[i] = (size_t)(n0 + r) * K + g * 8;
  }

  // fragment LDS offsets (ushort units), k0-independent
  int aoff[2][4], boff[2][4];
  #pragma unroll
  for (int mi = 0; mi < 2; ++mi){
    int r = wm + mi * 32 + l31;
    for (int kc = 0; kc < 4; ++kc)
      aoff[mi][kc] = r * 64 + ((kc * 2 + lh) ^ (r & 7)) * 8;
  }
  #pragma unroll
  for (int ni = 0; ni < 2; ++ni){
    int r = wn + ni * 32 + l31;
    for (int kc = 0; kc < 4; ++kc)
      boff[ni][kc] = r * 64 + ((kc * 2 + lh) ^ (r & 7)) * 8;
  }

  for (int k0 = 0; k0 < K; k0 += 64){
    __syncthreads();   // previous slab's readers done
    #pragma unroll
    for (int i = 0; i < 4; ++i)
      async16(&A[asrc[i] + k0], &As[(size_t)(256 * i + tid) * 8]);
    #pragma unroll
    for (int i = 0; i < 4; ++i)
      async16(&BT[bsrc[i] + k0], &Bs[(size_t)(256 * i + tid) * 8]);
    __syncthreads();   // drains vmcnt (compiler emits waitcnt before s_barrier)

    #pragma unroll
    for (int kc = 0; kc < 4; ++kc){
      bf16x8 af[2], bg[2];
      af[0] = *(const bf16x8*)&As[aoff[0][kc]];
      af[1] = *(const bf16x8*)&As[aoff[1][kc]];
      bg[0] = *(const bf16x8*)&Bs[boff[0][kc]];
      bg[1] = *(const bf16x8*)&Bs[boff[1][kc]];
      #pragma unroll
      for (int mi = 0; mi < 2; ++mi)
        #pragma unroll
        for (int ni = 0; ni < 2; ++ni)
          acc[mi][ni] = __builtin_amdgcn_mfma_f32_32x32x16_bf16(af[mi], bg[ni], acc[mi][ni], 0, 0, 0);
    }
  }

  // epilogue: 32x32 C/D layout col=lane&31, row=(reg&3)+8*(reg>>2)+4*(lane>>5)
  #pragma unroll
  for (int mi = 0; mi < 2; ++mi){
    #pragma unroll
    for (int ni = 0; ni < 2; ++ni){
      f32x16 v = acc[mi][ni];
      #pragma unroll
      for (int reg = 0; reg < 16; ++reg){
        int r = m0 + wm + mi * 32 + (reg & 3) + 8 * (reg >> 2) + 4 * lh;
        size_t idx = (size_t)r * N + n0 + wn + ni * 32 + l31;
        if (OUT_BF16) ((ushort_t*)Cout)[idx] = f2bf(v[reg]);
        else          ((float*)   Cout)[idx] = v[reg];
      }
    }
  }
}

// ---------------- fused segment attention ----------------
// grid (nseg=64, H=16, B=2), block 256 (4 waves).
// Qb:  [B*8192][1024] bf16, rows already in PERMUTED order (gemm1a GATHER=1).
// KV:  [B*4096][2048] bf16, rows in compacted dilated order seg*64+j
//      (gemm1b GATHER=2); cols 0..1023 = K, 1024..2047 = V.
// All loads contiguous; only the O-scatter applies hmap (involution inverse).
__global__ __launch_bounds__(256) void attn_kernel(const ushort_t* __restrict__ Qb,
                                                   const ushort_t* __restrict__ KV,
                                                   ushort_t* __restrict__ aout){
  __shared__ ushort_t Qs[128 * 72];   // reused as P after scores (wave-private rows)
  __shared__ ushort_t Ks[64 * 72];
  __shared__ ushort_t Vt[64 * 72];    // V transposed: Vt[d][kidx]
  int tid  = threadIdx.x;
  int lane = tid & 63, w = tid >> 6;
  int qd = lane >> 4, md = lane & 15;
  int seg = blockIdx.x, h = blockIdx.y, b = blockIdx.z;
  int p0 = seg * 128;

  // Q: 128 rows x 64 bf16 (8 chunks of 16B per row), contiguous rows
  for (int it = 0; it < 4; ++it){
    int q = it * 256 + tid;
    int r = q >> 3, ch = q & 7;
    uint4 d = *(const uint4*)&Qb[(size_t)(b * 8192 + p0 + r) * 1024 + h * 64 + ch * 8];
    *(uint4*)&Qs[r * 72 + ch * 8] = d;
  }
  // K: compacted rows seg*64 + r
  for (int it = 0; it < 2; ++it){
    int q = it * 256 + tid;
    int r = q >> 3, ch = q & 7;
    uint4 d = *(const uint4*)&KV[(size_t)(b * 4096 + seg * 64 + r) * 2048 + h * 64 + ch * 8];
    *(uint4*)&Ks[r * 72 + ch * 8] = d;
  }
  // V (cols 1024..2047), stored transposed for the PV B-operand
  for (int it = 0; it < 2; ++it){
    int q = it * 256 + tid;
    int r = q >> 3, ch = q & 7;
    union { uint4 v; ushort_t u[8]; } d;
    d.v = *(const uint4*)&KV[(size_t)(b * 4096 + seg * 64 + r) * 2048 + 1024 + h * 64 + ch * 8];
    for (int e = 0; e < 8; ++e) Vt[(ch * 8 + e) * 72 + r] = d.u[e];
  }
  __syncthreads();

  // scores: wave w owns q-rows [32w, 32w+32): 2 row-tiles x 4 col-tiles
  f32x4 z = {0.f, 0.f, 0.f, 0.f};
  f32x4 sc[2][4];
  for (int mi = 0; mi < 2; ++mi) for (int ni = 0; ni < 4; ++ni) sc[mi][ni] = z;
  for (int kc = 0; kc < 2; ++kc){
    bf16x8 aq[2], bk[4];
    for (int mi = 0; mi < 2; ++mi)
      aq[mi] = *(const bf16x8*)&Qs[(w * 32 + mi * 16 + md) * 72 + kc * 32 + qd * 8];
    for (int ni = 0; ni < 4; ++ni)
      bk[ni] = *(const bf16x8*)&Ks[(ni * 16 + md) * 72 + kc * 32 + qd * 8];
    for (int mi = 0; mi < 2; ++mi)
      for (int ni = 0; ni < 4; ++ni)
        sc[mi][ni] = __builtin_amdgcn_mfma_f32_16x16x32_bf16(aq[mi], bk[ni], sc[mi][ni], 0, 0, 0);
  }

  // softmax over 64 keys; scale 1/sqrt(64)=0.125. Row r lives in 16 lanes
  // (same quad) x 4 col-tiles -> in-register + shfl_xor(1,2,4,8) reduction.
  const float scale = 0.125f;
  ushort_t* Ps = Qs;  // alias: wave only touches its own 32 rows
  for (int mi = 0; mi < 2; ++mi){
    for (int i = 0; i < 4; ++i){
      float mx = sc[mi][0][i];
      for (int ni = 1; ni < 4; ++ni) mx = fmaxf(mx, sc[mi][ni][i]);
      for (int d = 1; d < 16; d <<= 1) mx = fmaxf(mx, __shfl_xor(mx, d));
      float e[4], sum = 0.f;
      for (int ni = 0; ni < 4; ++ni){ e[ni] = __expf((sc[mi][ni][i] - mx) * scale); sum += e[ni]; }
      for (int d = 1; d < 16; d <<= 1) sum += __shfl_xor(sum, d);
      float inv = 1.0f / sum;
      int r = w * 32 + mi * 16 + qd * 4 + i;
      for (int ni = 0; ni < 4; ++ni)
        Ps[r * 72 + ni * 16 + md] = f2bf(e[ni] * inv);
    }
  }

  // O = P @ V : A = P (rows w*32..+31), B = Vt[d][k]
  f32x4 oc[2][4];
  for (int mi = 0; mi < 2; ++mi) for (int ni = 0; ni < 4; ++ni) oc[mi][ni] = z;
  for (int kc = 0; kc < 2; ++kc){
    bf16x8 ap[2], bv[4];
    for (int mi = 0; mi < 2; ++mi)
      ap[mi] = *(const bf16x8*)&Ps[(w * 32 + mi * 16 + md) * 72 + kc * 32 + qd * 8];
    for (int ni = 0; ni < 4; ++ni)
      bv[ni] = *(const bf16x8*)&Vt[(ni * 16 + md) * 72 + kc * 32 + qd * 8];
    for (int mi = 0; mi < 2; ++mi)
      for (int ni = 0; ni < 4; ++ni)
        oc[mi][ni] = __builtin_amdgcn_mfma_f32_16x16x32_bf16(ap[mi], bv[ni], oc[mi][ni], 0, 0, 0);
  }

  // scatter back to natural seq order (inverse perm == hmap, involution)
  for (int mi = 0; mi < 2; ++mi){
    for (int i = 0; i < 4; ++i){
      int rl = w * 32 + mi * 16 + qd * 4 + i;
      int s  = hmap(p0 + rl);
      size_t base = (size_t)(b * 8192 + s) * 1024 + h * 64;
      for (int ni = 0; ni < 4; ++ni)
        aout[base + ni * 16 + md] = f2bf(oc[mi][ni][i]);
    }
  }
}

extern "C" void kernel_launch(void* const* d_in, const int* in_sizes, int n_in,
                              void* d_out, int out_size, void* d_ws, size_t ws_size,
                              hipStream_t stream){
  const float* x    = (const float*)d_in[0];   // [2,8192,1024]
  const float* Wqkv = (const float*)d_in[1];   // [1024,3072]
  const float* Wout = (const float*)d_in[2];   // [1024,1024]
  float* out = (float*)d_out;                  // [2,8192,1024]

  // ws layout (bytes): xb 32M | WqT 6M | WoT 2M | Qbuf 32M | KVbuf 32M | aout 32M = 136 MB
  char* ws = (char*)d_ws;
  ushort_t* xb    = (ushort_t*)(ws);
  ushort_t* WqT   = (ushort_t*)(ws + 33554432);
  ushort_t* WoT   = (ushort_t*)(ws + 39845888);
  ushort_t* Qbuf  = (ushort_t*)(ws + 41943040);
  ushort_t* KVbuf = (ushort_t*)(ws + 75497472);
  ushort_t* aoutb = (ushort_t*)(ws + 109051904);

  cast_kernel<<<16384, 256, 0, stream>>>(x, xb, (16384 * 1024) / 4);
  transpose_cast<<<dim3(48, 16), 256, 0, stream>>>(Wqkv, WqT, 1024, 3072);
  transpose_cast<<<dim3(16, 16), 256, 0, stream>>>(Wout, WoT, 1024, 1024);
  // Q projection: all rows, permuted output order
  gemm_bt<1, 1><<<dim3(8, 128), 256, 0, stream>>>(xb, WqT, Qbuf, 16384, 1024, 1024);
  // K,V projection: only dilated rows (half), compacted output order
  gemm_bt<1, 2><<<dim3(16, 64), 256, 0, stream>>>(xb, WqT + (size_t)1024 * 1024, KVbuf, 8192, 2048, 1024);
  attn_kernel<<<dim3(64, 16, 2), 256, 0, stream>>>(Qbuf, KVbuf, aoutb);
  gemm_bt<0, 0><<<dim3(8, 128), 256, 0, stream>>>(aoutb, WoT, out, 16384, 1024, 1024);
}

// Round 4
// 297.854 us; speedup vs baseline: 1.2042x; 1.0567x over previous
//
#include <hip/hip_runtime.h>
#include <stdint.h>

typedef unsigned short ushort_t;
typedef __bf16 bf16x8 __attribute__((ext_vector_type(8)));
typedef float  f32x4  __attribute__((ext_vector_type(4)));
typedef float  f32x16 __attribute__((ext_vector_type(16)));

#define DEV static __device__ __forceinline__

// fp32 -> bf16 round-to-nearest-even
DEV ushort_t f2bf(float f){
  union { float f; unsigned u; } x; x.f = f;
  unsigned u = x.u;
  return (ushort_t)((u + 0x7fffu + ((u >> 16) & 1u)) >> 16);
}

// Boustrophedon map for S=8192 (g=91): involution, maps permuted<->original.
DEV int hmap(int p){
  int r = p / 91;
  int c = p - r * 91;
  return (r & 1) ? (r * 91 + 90 - c) : p;
}

// async global->LDS 16B per lane (LDS dest must be uniform base + lane*16)
DEV void async16(const void* g, void* l){
  __builtin_amdgcn_global_load_lds(
      (const __attribute__((address_space(1))) unsigned*)g,
      (__attribute__((address_space(3))) unsigned*)l, 16, 0, 0);
}

// A-row gather modes: 0 identity; 1 = Q permuted order (row p of batch b reads
// natural row hmap(p)); 2 = compacted dilated KV order (row seg*64+j of batch b
// reads natural row hmap(seg*128+2j)).
template<int GATHER>
DEV int arow_map(int r){
  if (GATHER == 0) return r;
  if (GATHER == 1){ int b = r >> 13, p = r & 8191; return b * 8192 + hmap(p); }
  int b = r >> 12, rem = r & 4095, seg = rem >> 6, j = rem & 63;
  return b * 8192 + hmap(seg * 128 + 2 * j);
}

// ---------------- cast x (fp32 -> bf16), vectorized ----------------
__global__ void cast_kernel(const float* __restrict__ in, ushort_t* __restrict__ out, int n4){
  int i = blockIdx.x * blockDim.x + threadIdx.x;
  if (i < n4){
    float4 v = ((const float4*)in)[i];
    ushort4 o;
    o.x = f2bf(v.x); o.y = f2bf(v.y); o.z = f2bf(v.z); o.w = f2bf(v.w);
    ((ushort4*)out)[i] = o;
  }
}

// ---------- transpose + cast: W [rows][cols] fp32 -> WT [cols][rows] bf16 ----------
__global__ void transpose_cast(const float* __restrict__ W, ushort_t* __restrict__ WT,
                               int rows, int cols){
  __shared__ ushort_t t[64 * 66];   // pad 66: conflict-free column reads
  int tid = threadIdx.x;
  int c0 = blockIdx.x * 64, r0 = blockIdx.y * 64;
  int cl = tid & 63, rb = tid >> 6;
  for (int i = 0; i < 16; ++i){
    int r = rb + i * 4;
    t[r * 66 + cl] = f2bf(W[(size_t)(r0 + r) * cols + c0 + cl]);
  }
  __syncthreads();
  int rr = tid & 63, cb = tid >> 6;
  for (int i = 0; i < 16; ++i){
    int cc = cb + i * 4;
    WT[(size_t)(c0 + cc) * rows + r0 + rr] = t[rr * 66 + cc];
  }
}

// ---------------- GEMM: C[M][N] = A[gather(M)][K] * BT[N][K]^T ----------------
// 128x128 tile, BK=64, 4 waves, each wave a 64x64 quadrant of 2x2 mfma
// 32x32x16 tiles. LDS rows: 64 elems = 8 x 16B chunks, physical slot =
// chunk ^ (row&7). XCD-aware block remap: XCD (flat&7) owns a contiguous
// stripe of gy/8 m-tiles, iterated as sub-stripes of 4 m-tiles x all n-tiles
// -> per-XCD L2 working set ~1MB A + full B; A fetched from HBM once chip-wide.
template<int OUT_BF16, int GATHER>
__global__ __launch_bounds__(256) void gemm_bt(const ushort_t* __restrict__ A,
                                               const ushort_t* __restrict__ BT,
                                               void* __restrict__ Cout,
                                               int M, int N, int K){
  __shared__ ushort_t As[128 * 64];
  __shared__ ushort_t Bs[128 * 64];
  int tid  = threadIdx.x;
  int lane = tid & 63, w = tid >> 6;
  int l31 = lane & 31, lh = lane >> 5;

  // block remap (requires gy % 8 == 0)
  int nx = gridDim.x, gy = gridDim.y;
  int flat = blockIdx.y * nx + blockIdx.x;
  int xcd = flat & 7, lid = flat >> 3;
  int chunk = nx * 4;
  int sub = lid / chunk, rem = lid - sub * chunk;
  int mt = xcd * (gy >> 3) + sub * 4 + (rem & 3);
  int nt = rem >> 2;
  int m0 = mt * 128, n0 = nt * 128;

  int wm = (w >> 1) * 64, wn = (w & 1) * 64;

  f32x16 acc[2][2];
  for (int a = 0; a < 4; ++a) for (int b = 0; b < 16; ++b) acc[a >> 1][a & 1][b] = 0.f;

  // staging plan: instr i (0..3) covers linear chunk q=256*i+tid ->
  // row = 32*i + (tid>>3), dest slot = tid&7, global chunk = slot ^ (row&7).
  int rbase = tid >> 3, slot = tid & 7;
  size_t asrc[4], bsrc[4];
  #pragma unroll
  for (int i = 0; i < 4; ++i){
    int r = rbase + 32 * i;
    int g = slot ^ (r & 7);
    asrc[i] = (size_t)arow_map<GATHER>(m0 + r) * K + g * 8;
    bsrc[i] = (size_t)(n0 + r) * K + g * 8;
  }

  // fragment LDS offsets (ushort units), k0-independent
  int aoff[2][4], boff[2][4];
  #pragma unroll
  for (int mi = 0; mi < 2; ++mi){
    int r = wm + mi * 32 + l31;
    for (int kc = 0; kc < 4; ++kc)
      aoff[mi][kc] = r * 64 + ((kc * 2 + lh) ^ (r & 7)) * 8;
  }
  #pragma unroll
  for (int ni = 0; ni < 2; ++ni){
    int r = wn + ni * 32 + l31;
    for (int kc = 0; kc < 4; ++kc)
      boff[ni][kc] = r * 64 + ((kc * 2 + lh) ^ (r & 7)) * 8;
  }

  for (int k0 = 0; k0 < K; k0 += 64){
    __syncthreads();   // previous slab's readers done
    #pragma unroll
    for (int i = 0; i < 4; ++i)
      async16(&A[asrc[i] + k0], &As[(size_t)(256 * i + tid) * 8]);
    #pragma unroll
    for (int i = 0; i < 4; ++i)
      async16(&BT[bsrc[i] + k0], &Bs[(size_t)(256 * i + tid) * 8]);
    __syncthreads();   // drains vmcnt (compiler emits waitcnt before s_barrier)

    #pragma unroll
    for (int kc = 0; kc < 4; ++kc){
      bf16x8 af[2], bg[2];
      af[0] = *(const bf16x8*)&As[aoff[0][kc]];
      af[1] = *(const bf16x8*)&As[aoff[1][kc]];
      bg[0] = *(const bf16x8*)&Bs[boff[0][kc]];
      bg[1] = *(const bf16x8*)&Bs[boff[1][kc]];
      #pragma unroll
      for (int mi = 0; mi < 2; ++mi)
        #pragma unroll
        for (int ni = 0; ni < 2; ++ni)
          acc[mi][ni] = __builtin_amdgcn_mfma_f32_32x32x16_bf16(af[mi], bg[ni], acc[mi][ni], 0, 0, 0);
    }
  }

  // epilogue: 32x32 C/D layout col=lane&31, row=(reg&3)+8*(reg>>2)+4*(lane>>5)
  #pragma unroll
  for (int mi = 0; mi < 2; ++mi){
    #pragma unroll
    for (int ni = 0; ni < 2; ++ni){
      f32x16 v = acc[mi][ni];
      #pragma unroll
      for (int reg = 0; reg < 16; ++reg){
        int r = m0 + wm + mi * 32 + (reg & 3) + 8 * (reg >> 2) + 4 * lh;
        size_t idx = (size_t)r * N + n0 + wn + ni * 32 + l31;
        if (OUT_BF16) ((ushort_t*)Cout)[idx] = f2bf(v[reg]);
        else          ((float*)   Cout)[idx] = v[reg];
      }
    }
  }
}

// ---------------- fused segment attention ----------------
// grid (nseg=64, H=16, B=2), block 256 (4 waves).
// Qb:  [B*8192][1024] bf16, rows already in PERMUTED order (gemm1a GATHER=1).
// KV:  [B*4096][2048] bf16, rows in compacted dilated order seg*64+j
//      (gemm1b GATHER=2); cols 0..1023 = K, 1024..2047 = V.
// All loads contiguous; O goes through LDS so global stores are 16B coalesced;
// only the O row index applies hmap (involution inverse).
__global__ __launch_bounds__(256) void attn_kernel(const ushort_t* __restrict__ Qb,
                                                   const ushort_t* __restrict__ KV,
                                                   ushort_t* __restrict__ aout){
  __shared__ ushort_t Qs[128 * 72];   // reused as P, then as O (wave-private rows)
  __shared__ ushort_t Ks[64 * 72];
  __shared__ ushort_t Vt[64 * 72];    // V transposed: Vt[d][kidx]
  int tid  = threadIdx.x;
  int lane = tid & 63, w = tid >> 6;
  int qd = lane >> 4, md = lane & 15;
  int seg = blockIdx.x, h = blockIdx.y, b = blockIdx.z;
  int p0 = seg * 128;

  // Q: 128 rows x 64 bf16 (8 chunks of 16B per row), contiguous rows
  for (int it = 0; it < 4; ++it){
    int q = it * 256 + tid;
    int r = q >> 3, ch = q & 7;
    uint4 d = *(const uint4*)&Qb[(size_t)(b * 8192 + p0 + r) * 1024 + h * 64 + ch * 8];
    *(uint4*)&Qs[r * 72 + ch * 8] = d;
  }
  // K: compacted rows seg*64 + r
  for (int it = 0; it < 2; ++it){
    int q = it * 256 + tid;
    int r = q >> 3, ch = q & 7;
    uint4 d = *(const uint4*)&KV[(size_t)(b * 4096 + seg * 64 + r) * 2048 + h * 64 + ch * 8];
    *(uint4*)&Ks[r * 72 + ch * 8] = d;
  }
  // V (cols 1024..2047), stored transposed for the PV B-operand
  for (int it = 0; it < 2; ++it){
    int q = it * 256 + tid;
    int r = q >> 3, ch = q & 7;
    union { uint4 v; ushort_t u[8]; } d;
    d.v = *(const uint4*)&KV[(size_t)(b * 4096 + seg * 64 + r) * 2048 + 1024 + h * 64 + ch * 8];
    for (int e = 0; e < 8; ++e) Vt[(ch * 8 + e) * 72 + r] = d.u[e];
  }
  __syncthreads();

  // scores: wave w owns q-rows [32w, 32w+32): 2 row-tiles x 4 col-tiles
  f32x4 z = {0.f, 0.f, 0.f, 0.f};
  f32x4 sc[2][4];
  for (int mi = 0; mi < 2; ++mi) for (int ni = 0; ni < 4; ++ni) sc[mi][ni] = z;
  for (int kc = 0; kc < 2; ++kc){
    bf16x8 aq[2], bk[4];
    for (int mi = 0; mi < 2; ++mi)
      aq[mi] = *(const bf16x8*)&Qs[(w * 32 + mi * 16 + md) * 72 + kc * 32 + qd * 8];
    for (int ni = 0; ni < 4; ++ni)
      bk[ni] = *(const bf16x8*)&Ks[(ni * 16 + md) * 72 + kc * 32 + qd * 8];
    for (int mi = 0; mi < 2; ++mi)
      for (int ni = 0; ni < 4; ++ni)
        sc[mi][ni] = __builtin_amdgcn_mfma_f32_16x16x32_bf16(aq[mi], bk[ni], sc[mi][ni], 0, 0, 0);
  }

  // softmax over 64 keys; scale 1/sqrt(64)=0.125. Row r lives in 16 lanes
  // (same quad) x 4 col-tiles -> in-register + shfl_xor(1,2,4,8) reduction.
  const float scale = 0.125f;
  ushort_t* Ps = Qs;  // alias: wave only touches its own 32 rows
  for (int mi = 0; mi < 2; ++mi){
    for (int i = 0; i < 4; ++i){
      float mx = sc[mi][0][i];
      for (int ni = 1; ni < 4; ++ni) mx = fmaxf(mx, sc[mi][ni][i]);
      for (int d = 1; d < 16; d <<= 1) mx = fmaxf(mx, __shfl_xor(mx, d));
      float e[4], sum = 0.f;
      for (int ni = 0; ni < 4; ++ni){ e[ni] = __expf((sc[mi][ni][i] - mx) * scale); sum += e[ni]; }
      for (int d = 1; d < 16; d <<= 1) sum += __shfl_xor(sum, d);
      float inv = 1.0f / sum;
      int r = w * 32 + mi * 16 + qd * 4 + i;
      for (int ni = 0; ni < 4; ++ni)
        Ps[r * 72 + ni * 16 + md] = f2bf(e[ni] * inv);
    }
  }

  // O = P @ V : A = P (rows w*32..+31), B = Vt[d][k]
  f32x4 oc[2][4];
  for (int mi = 0; mi < 2; ++mi) for (int ni = 0; ni < 4; ++ni) oc[mi][ni] = z;
  for (int kc = 0; kc < 2; ++kc){
    bf16x8 ap[2], bv[4];
    for (int mi = 0; mi < 2; ++mi)
      ap[mi] = *(const bf16x8*)&Ps[(w * 32 + mi * 16 + md) * 72 + kc * 32 + qd * 8];
    for (int ni = 0; ni < 4; ++ni)
      bv[ni] = *(const bf16x8*)&Vt[(ni * 16 + md) * 72 + kc * 32 + qd * 8];
    for (int mi = 0; mi < 2; ++mi)
      for (int ni = 0; ni < 4; ++ni)
        oc[mi][ni] = __builtin_amdgcn_mfma_f32_16x16x32_bf16(ap[mi], bv[ni], oc[mi][ni], 0, 0, 0);
  }

  // O back into wave-private LDS rows (overwrites this wave's P), then
  // one barrier and fully-coalesced 16B stores: row s=hmap(p0+r), 128B/row.
  for (int mi = 0; mi < 2; ++mi){
    for (int i = 0; i < 4; ++i){
      int rl = w * 32 + mi * 16 + qd * 4 + i;
      for (int ni = 0; ni < 4; ++ni)
        Ps[rl * 72 + ni * 16 + md] = f2bf(oc[mi][ni][i]);
    }
  }
  __syncthreads();
  for (int it = 0; it < 4; ++it){
    int q = it * 256 + tid;
    int r = q >> 3, ch = q & 7;
    int s = hmap(p0 + r);
    *(uint4*)&aout[(size_t)(b * 8192 + s) * 1024 + h * 64 + ch * 8] =
        *(const uint4*)&Qs[r * 72 + ch * 8];
  }
}

extern "C" void kernel_launch(void* const* d_in, const int* in_sizes, int n_in,
                              void* d_out, int out_size, void* d_ws, size_t ws_size,
                              hipStream_t stream){
  const float* x    = (const float*)d_in[0];   // [2,8192,1024]
  const float* Wqkv = (const float*)d_in[1];   // [1024,3072]
  const float* Wout = (const float*)d_in[2];   // [1024,1024]
  float* out = (float*)d_out;                  // [2,8192,1024]

  // ws layout (bytes): xb 32M | WqT 6M | WoT 2M | Qbuf 32M | KVbuf 32M | aout 32M = 136 MB
  char* ws = (char*)d_ws;
  ushort_t* xb    = (ushort_t*)(ws);
  ushort_t* WqT   = (ushort_t*)(ws + 33554432);
  ushort_t* WoT   = (ushort_t*)(ws + 39845888);
  ushort_t* Qbuf  = (ushort_t*)(ws + 41943040);
  ushort_t* KVbuf = (ushort_t*)(ws + 75497472);
  ushort_t* aoutb = (ushort_t*)(ws + 109051904);

  cast_kernel<<<16384, 256, 0, stream>>>(x, xb, (16384 * 1024) / 4);
  transpose_cast<<<dim3(48, 16), 256, 0, stream>>>(Wqkv, WqT, 1024, 3072);
  transpose_cast<<<dim3(16, 16), 256, 0, stream>>>(Wout, WoT, 1024, 1024);
  // Q projection: all rows, permuted output order
  gemm_bt<1, 1><<<dim3(8, 128), 256, 0, stream>>>(xb, WqT, Qbuf, 16384, 1024, 1024);
  // K,V projection: only dilated rows (half), compacted output order
  gemm_bt<1, 2><<<dim3(16, 64), 256, 0, stream>>>(xb, WqT + (size_t)1024 * 1024, KVbuf, 8192, 2048, 1024);
  attn_kernel<<<dim3(64, 16, 2), 256, 0, stream>>>(Qbuf, KVbuf, aoutb);
  gemm_bt<0, 0><<<dim3(8, 128), 256, 0, stream>>>(aoutb, WoT, out, 16384, 1024, 1024);
}

// Round 5
// 278.440 us; speedup vs baseline: 1.2882x; 1.0697x over previous
//
#include <hip/hip_runtime.h>
#include <stdint.h>

typedef unsigned short ushort_t;
typedef __bf16 bf16x8 __attribute__((ext_vector_type(8)));
typedef float  f32x4  __attribute__((ext_vector_type(4)));
typedef float  f32x16 __attribute__((ext_vector_type(16)));

#define DEV static __device__ __forceinline__

// fp32 -> bf16 round-to-nearest-even
DEV ushort_t f2bf(float f){
  union { float f; unsigned u; } x; x.f = f;
  unsigned u = x.u;
  return (ushort_t)((u + 0x7fffu + ((u >> 16) & 1u)) >> 16);
}

// Boustrophedon map for S=8192 (g=91): involution, maps permuted<->original.
DEV int hmap(int p){
  int r = p / 91;
  int c = p - r * 91;
  return (r & 1) ? (r * 91 + 90 - c) : p;
}

// async global->LDS 16B per lane (LDS dest must be uniform base + lane*16)
DEV void async16(const void* g, void* l){
  __builtin_amdgcn_global_load_lds(
      (const __attribute__((address_space(1))) unsigned*)g,
      (__attribute__((address_space(3))) unsigned*)l, 16, 0, 0);
}

// A-row gather modes: 0 identity; 1 = Q permuted order (row p of batch b reads
// natural row hmap(p)); 2 = compacted dilated KV order (row seg*64+j of batch b
// reads natural row hmap(seg*128+2j)).
template<int GATHER>
DEV int arow_map(int r){
  if (GATHER == 0) return r;
  if (GATHER == 1){ int b = r >> 13, p = r & 8191; return b * 8192 + hmap(p); }
  int b = r >> 12, rem = r & 4095, seg = rem >> 6, j = rem & 63;
  return b * 8192 + hmap(seg * 128 + 2 * j);
}

// ---------------- cast x (fp32 -> bf16), vectorized ----------------
__global__ void cast_kernel(const float* __restrict__ in, ushort_t* __restrict__ out, int n4){
  int i = blockIdx.x * blockDim.x + threadIdx.x;
  if (i < n4){
    float4 v = ((const float4*)in)[i];
    ushort4 o;
    o.x = f2bf(v.x); o.y = f2bf(v.y); o.z = f2bf(v.z); o.w = f2bf(v.w);
    ((ushort4*)out)[i] = o;
  }
}

// ---------- transpose + cast: W [rows][cols] fp32 -> WT [cols][rows] bf16 ----------
__global__ void transpose_cast(const float* __restrict__ W, ushort_t* __restrict__ WT,
                               int rows, int cols){
  __shared__ ushort_t t[64 * 66];   // pad 66: conflict-free column reads
  int tid = threadIdx.x;
  int c0 = blockIdx.x * 64, r0 = blockIdx.y * 64;
  int cl = tid & 63, rb = tid >> 6;
  for (int i = 0; i < 16; ++i){
    int r = rb + i * 4;
    t[r * 66 + cl] = f2bf(W[(size_t)(r0 + r) * cols + c0 + cl]);
  }
  __syncthreads();
  int rr = tid & 63, cb = tid >> 6;
  for (int i = 0; i < 16; ++i){
    int cc = cb + i * 4;
    WT[(size_t)(c0 + cc) * rows + r0 + rr] = t[rr * 66 + cc];
  }
}

// ---------------- GEMM: C[M][N] = A[gather(M)][K] * BT[N][K]^T ----------------
// Tile 128(m) x 256(n), BK=64. Staged bytes/slab = 48 KB for 4.2 MFLOP
// (87 FLOP/B, vs 64 at 128x128) and A is re-staged only N/256 times -> the
// L3-service traffic that bounded R3 (512 MB -> ~160 MB). 1-D grid, n-major
// order: concurrent blocks share one 0.5 MB B-tile (L2-resident); A streams.
// 4 waves, each 64x128 (acc 2x4 f32x16). LDS 48 KB -> 2 blocks/CU.
// LDS rows: 64 elems = 8 x 16B chunks, slot = chunk ^ (row&7) (conflict-free
// fragment reads, contiguous global_load_lds dest).
template<int OUT_BF16, int GATHER>
__global__ __launch_bounds__(256, 2) void gemm_bt(const ushort_t* __restrict__ A,
                                                  const ushort_t* __restrict__ BT,
                                                  void* __restrict__ Cout,
                                                  int M, int N, int K){
  __shared__ ushort_t As[128 * 64];
  __shared__ ushort_t Bs[256 * 64];
  int tid  = threadIdx.x;
  int lane = tid & 63, w = tid >> 6;
  int l31 = lane & 31, lh = lane >> 5;

  int mtc = M >> 7;                 // m-tiles
  int o  = blockIdx.x;
  int nt = o / mtc, mt = o - nt * mtc;   // n-major: consecutive ids share nt
  int m0 = mt * 128, n0 = nt * 256;

  int wm = (w >> 1) * 64, wn = (w & 1) * 128;

  f32x16 acc[2][4];
  #pragma unroll
  for (int a = 0; a < 8; ++a)
    #pragma unroll
    for (int b = 0; b < 16; ++b) acc[a >> 2][a & 3][b] = 0.f;

  // staging: instr i covers rows 32i..32i+31: row = 32i + (tid>>3),
  // dest slot = tid&7, global chunk g = slot ^ (row&7); (32i & 7)==0 so g is
  // i-independent for B (contiguous rows) but A needs per-i gather rows.
  int rbase = tid >> 3, slot = tid & 7;
  int g0 = (slot ^ (rbase & 7)) * 8;
  size_t asrc[4];
  #pragma unroll
  for (int i = 0; i < 4; ++i)
    asrc[i] = (size_t)arow_map<GATHER>(m0 + rbase + 32 * i) * K + g0;
  size_t bsrc0 = (size_t)(n0 + rbase) * K + g0;

  // fragment LDS offsets (ushort units), k0-independent
  int aoff[2][4], boff[4][4];
  #pragma unroll
  for (int mi = 0; mi < 2; ++mi){
    int r = wm + mi * 32 + l31;
    #pragma unroll
    for (int kc = 0; kc < 4; ++kc)
      aoff[mi][kc] = r * 64 + ((kc * 2 + lh) ^ (r & 7)) * 8;
  }
  #pragma unroll
  for (int ni = 0; ni < 4; ++ni){
    int r = wn + ni * 32 + l31;
    #pragma unroll
    for (int kc = 0; kc < 4; ++kc)
      boff[ni][kc] = r * 64 + ((kc * 2 + lh) ^ (r & 7)) * 8;
  }

  for (int k0 = 0; k0 < K; k0 += 64){
    __syncthreads();   // previous slab's readers done
    #pragma unroll
    for (int i = 0; i < 4; ++i)
      async16(&A[asrc[i] + k0], &As[(size_t)(256 * i + tid) * 8]);
    #pragma unroll
    for (int i = 0; i < 8; ++i)
      async16(&BT[bsrc0 + (size_t)(32 * i) * K + k0], &Bs[(size_t)(256 * i + tid) * 8]);
    __syncthreads();   // drains vmcnt (compiler emits waitcnt before s_barrier)

    #pragma unroll
    for (int kc = 0; kc < 4; ++kc){
      bf16x8 af[2], bg[4];
      af[0] = *(const bf16x8*)&As[aoff[0][kc]];
      af[1] = *(const bf16x8*)&As[aoff[1][kc]];
      #pragma unroll
      for (int ni = 0; ni < 4; ++ni)
        bg[ni] = *(const bf16x8*)&Bs[boff[ni][kc]];
      #pragma unroll
      for (int mi = 0; mi < 2; ++mi)
        #pragma unroll
        for (int ni = 0; ni < 4; ++ni)
          acc[mi][ni] = __builtin_amdgcn_mfma_f32_32x32x16_bf16(af[mi], bg[ni], acc[mi][ni], 0, 0, 0);
    }
  }

  // epilogue: 32x32 C/D layout col=lane&31, row=(reg&3)+8*(reg>>2)+4*(lane>>5)
  #pragma unroll
  for (int mi = 0; mi < 2; ++mi){
    #pragma unroll
    for (int ni = 0; ni < 4; ++ni){
      f32x16 v = acc[mi][ni];
      #pragma unroll
      for (int reg = 0; reg < 16; ++reg){
        int r = m0 + wm + mi * 32 + (reg & 3) + 8 * (reg >> 2) + 4 * lh;
        size_t idx = (size_t)r * N + n0 + wn + ni * 32 + l31;
        if (OUT_BF16) ((ushort_t*)Cout)[idx] = f2bf(v[reg]);
        else          ((float*)   Cout)[idx] = v[reg];
      }
    }
  }
}

// ---------------- fused segment attention ----------------
// grid (nseg=64, H=16, B=2), block 256 (4 waves).
// Qb:  [B*8192][1024] bf16, rows already in PERMUTED order (gemm1a GATHER=1).
// KV:  [B*4096][2048] bf16, rows in compacted dilated order seg*64+j
//      (gemm1b GATHER=2); cols 0..1023 = K, 1024..2047 = V.
// All loads contiguous; O goes through LDS so global stores are 16B coalesced;
// only the O row index applies hmap (involution inverse).
__global__ __launch_bounds__(256) void attn_kernel(const ushort_t* __restrict__ Qb,
                                                   const ushort_t* __restrict__ KV,
                                                   ushort_t* __restrict__ aout){
  __shared__ ushort_t Qs[128 * 72];   // reused as P, then as O (wave-private rows)
  __shared__ ushort_t Ks[64 * 72];
  __shared__ ushort_t Vt[64 * 72];    // V transposed: Vt[d][kidx]
  int tid  = threadIdx.x;
  int lane = tid & 63, w = tid >> 6;
  int qd = lane >> 4, md = lane & 15;
  int seg = blockIdx.x, h = blockIdx.y, b = blockIdx.z;
  int p0 = seg * 128;

  // Q: 128 rows x 64 bf16 (8 chunks of 16B per row), contiguous rows
  for (int it = 0; it < 4; ++it){
    int q = it * 256 + tid;
    int r = q >> 3, ch = q & 7;
    uint4 d = *(const uint4*)&Qb[(size_t)(b * 8192 + p0 + r) * 1024 + h * 64 + ch * 8];
    *(uint4*)&Qs[r * 72 + ch * 8] = d;
  }
  // K: compacted rows seg*64 + r
  for (int it = 0; it < 2; ++it){
    int q = it * 256 + tid;
    int r = q >> 3, ch = q & 7;
    uint4 d = *(const uint4*)&KV[(size_t)(b * 4096 + seg * 64 + r) * 2048 + h * 64 + ch * 8];
    *(uint4*)&Ks[r * 72 + ch * 8] = d;
  }
  // V (cols 1024..2047), stored transposed for the PV B-operand
  for (int it = 0; it < 2; ++it){
    int q = it * 256 + tid;
    int r = q >> 3, ch = q & 7;
    union { uint4 v; ushort_t u[8]; } d;
    d.v = *(const uint4*)&KV[(size_t)(b * 4096 + seg * 64 + r) * 2048 + 1024 + h * 64 + ch * 8];
    for (int e = 0; e < 8; ++e) Vt[(ch * 8 + e) * 72 + r] = d.u[e];
  }
  __syncthreads();

  // scores: wave w owns q-rows [32w, 32w+32): 2 row-tiles x 4 col-tiles
  f32x4 z = {0.f, 0.f, 0.f, 0.f};
  f32x4 sc[2][4];
  for (int mi = 0; mi < 2; ++mi) for (int ni = 0; ni < 4; ++ni) sc[mi][ni] = z;
  for (int kc = 0; kc < 2; ++kc){
    bf16x8 aq[2], bk[4];
    for (int mi = 0; mi < 2; ++mi)
      aq[mi] = *(const bf16x8*)&Qs[(w * 32 + mi * 16 + md) * 72 + kc * 32 + qd * 8];
    for (int ni = 0; ni < 4; ++ni)
      bk[ni] = *(const bf16x8*)&Ks[(ni * 16 + md) * 72 + kc * 32 + qd * 8];
    for (int mi = 0; mi < 2; ++mi)
      for (int ni = 0; ni < 4; ++ni)
        sc[mi][ni] = __builtin_amdgcn_mfma_f32_16x16x32_bf16(aq[mi], bk[ni], sc[mi][ni], 0, 0, 0);
  }

  // softmax over 64 keys; scale 1/sqrt(64)=0.125. Row r lives in 16 lanes
  // (same quad) x 4 col-tiles -> in-register + shfl_xor(1,2,4,8) reduction.
  const float scale = 0.125f;
  ushort_t* Ps = Qs;  // alias: wave only touches its own 32 rows
  for (int mi = 0; mi < 2; ++mi){
    for (int i = 0; i < 4; ++i){
      float mx = sc[mi][0][i];
      for (int ni = 1; ni < 4; ++ni) mx = fmaxf(mx, sc[mi][ni][i]);
      for (int d = 1; d < 16; d <<= 1) mx = fmaxf(mx, __shfl_xor(mx, d));
      float e[4], sum = 0.f;
      for (int ni = 0; ni < 4; ++ni){ e[ni] = __expf((sc[mi][ni][i] - mx) * scale); sum += e[ni]; }
      for (int d = 1; d < 16; d <<= 1) sum += __shfl_xor(sum, d);
      float inv = 1.0f / sum;
      int r = w * 32 + mi * 16 + qd * 4 + i;
      for (int ni = 0; ni < 4; ++ni)
        Ps[r * 72 + ni * 16 + md] = f2bf(e[ni] * inv);
    }
  }

  // O = P @ V : A = P (rows w*32..+31), B = Vt[d][k]
  f32x4 oc[2][4];
  for (int mi = 0; mi < 2; ++mi) for (int ni = 0; ni < 4; ++ni) oc[mi][ni] = z;
  for (int kc = 0; kc < 2; ++kc){
    bf16x8 ap[2], bv[4];
    for (int mi = 0; mi < 2; ++mi)
      ap[mi] = *(const bf16x8*)&Ps[(w * 32 + mi * 16 + md) * 72 + kc * 32 + qd * 8];
    for (int ni = 0; ni < 4; ++ni)
      bv[ni] = *(const bf16x8*)&Vt[(ni * 16 + md) * 72 + kc * 32 + qd * 8];
    for (int mi = 0; mi < 2; ++mi)
      for (int ni = 0; ni < 4; ++ni)
        oc[mi][ni] = __builtin_amdgcn_mfma_f32_16x16x32_bf16(ap[mi], bv[ni], oc[mi][ni], 0, 0, 0);
  }

  // O back into wave-private LDS rows (overwrites this wave's P), then
  // one barrier and fully-coalesced 16B stores: row s=hmap(p0+r), 128B/row.
  for (int mi = 0; mi < 2; ++mi){
    for (int i = 0; i < 4; ++i){
      int rl = w * 32 + mi * 16 + qd * 4 + i;
      for (int ni = 0; ni < 4; ++ni)
        Ps[rl * 72 + ni * 16 + md] = f2bf(oc[mi][ni][i]);
    }
  }
  __syncthreads();
  for (int it = 0; it < 4; ++it){
    int q = it * 256 + tid;
    int r = q >> 3, ch = q & 7;
    int s = hmap(p0 + r);
    *(uint4*)&aout[(size_t)(b * 8192 + s) * 1024 + h * 64 + ch * 8] =
        *(const uint4*)&Qs[r * 72 + ch * 8];
  }
}

extern "C" void kernel_launch(void* const* d_in, const int* in_sizes, int n_in,
                              void* d_out, int out_size, void* d_ws, size_t ws_size,
                              hipStream_t stream){
  const float* x    = (const float*)d_in[0];   // [2,8192,1024]
  const float* Wqkv = (const float*)d_in[1];   // [1024,3072]
  const float* Wout = (const float*)d_in[2];   // [1024,1024]
  float* out = (float*)d_out;                  // [2,8192,1024]

  // ws layout (bytes): xb 32M | WqT 6M | WoT 2M | Qbuf 32M | KVbuf 32M | aout 32M = 136 MB
  char* ws = (char*)d_ws;
  ushort_t* xb    = (ushort_t*)(ws);
  ushort_t* WqT   = (ushort_t*)(ws + 33554432);
  ushort_t* WoT   = (ushort_t*)(ws + 39845888);
  ushort_t* Qbuf  = (ushort_t*)(ws + 41943040);
  ushort_t* KVbuf = (ushort_t*)(ws + 75497472);
  ushort_t* aoutb = (ushort_t*)(ws + 109051904);

  cast_kernel<<<16384, 256, 0, stream>>>(x, xb, (16384 * 1024) / 4);
  transpose_cast<<<dim3(48, 16), 256, 0, stream>>>(Wqkv, WqT, 1024, 3072);
  transpose_cast<<<dim3(16, 16), 256, 0, stream>>>(Wout, WoT, 1024, 1024);
  // Q projection: all rows, permuted output order. grid = (N/256)*(M/128)
  gemm_bt<1, 1><<<4 * 128, 256, 0, stream>>>(xb, WqT, Qbuf, 16384, 1024, 1024);
  // K,V projection: only dilated rows (half), compacted output order
  gemm_bt<1, 2><<<8 * 64, 256, 0, stream>>>(xb, WqT + (size_t)1024 * 1024, KVbuf, 8192, 2048, 1024);
  attn_kernel<<<dim3(64, 16, 2), 256, 0, stream>>>(Qbuf, KVbuf, aoutb);
  gemm_bt<0, 0><<<4 * 128, 256, 0, stream>>>(aoutb, WoT, out, 16384, 1024, 1024);
}